// Round 8
// baseline (820.900 us; speedup 1.0000x reference)
//
#include <hip/hip_runtime.h>
#include <hip/hip_bf16.h>

// Problem constants
constexpr int NB  = 4;     // batch
constexpr int NS  = 2048;  // sequence
constexpr int NH  = 8;     // heads
constexpr int DM  = 512;   // d_model
constexpr int DKV = 64;    // d_k = d_v
constexpr int HB  = NH * NB; // 32 (h,b) slices

typedef __attribute__((ext_vector_type(8))) short short8;
typedef __attribute__((ext_vector_type(4))) float f32x4;

__device__ inline unsigned short f2bf(float f) {
    unsigned u = __builtin_bit_cast(unsigned, f);
    u = (u + 0x7fffu + ((u >> 16) & 1u)) >> 16;   // RNE, finite inputs
    return (unsigned short)u;
}
__device__ inline float bf2f(unsigned short h) {
    unsigned u = ((unsigned)h) << 16;
    return __builtin_bit_cast(float, u);
}
__device__ inline short8 ld8(const unsigned short* p) { return *(const short8*)p; }

// Load 8 consecutive fp32, convert to bf16x8 fragment
__device__ inline short8 pack8(const float* p) {
    f32x4 a = *(const f32x4*)p;
    f32x4 b = *(const f32x4*)(p + 4);
    short8 r;
    r[0] = (short)f2bf(a[0]); r[1] = (short)f2bf(a[1]);
    r[2] = (short)f2bf(a[2]); r[3] = (short)f2bf(a[3]);
    r[4] = (short)f2bf(b[0]); r[5] = (short)f2bf(b[1]);
    r[6] = (short)f2bf(b[2]); r[7] = (short)f2bf(b[3]);
    return r;
}

__device__ inline f32x4 mfma16(short8 a, short8 b, f32x4 c) {
    return __builtin_amdgcn_mfma_f32_16x16x32_bf16(a, b, c, 0, 0, 0);
}

// ---------------------------------------------------------------------------
// Convert fp32 -> bf16: y<3: activations q/k/v (4M elems each, 2048 blocks);
// y==3: the four 512x512 weight matrices (128 blocks each, 512 total).
// ---------------------------------------------------------------------------
__global__ __launch_bounds__(256) void k_cvt(const float* __restrict__ x0,
                                             const float* __restrict__ x1,
                                             const float* __restrict__ x2,
                                             const float* __restrict__ w0,
                                             const float* __restrict__ w1,
                                             const float* __restrict__ w2,
                                             const float* __restrict__ w3,
                                             unsigned short* __restrict__ dx0,
                                             unsigned short* __restrict__ dx1,
                                             unsigned short* __restrict__ dx2,
                                             unsigned short* __restrict__ dw0,
                                             unsigned short* __restrict__ dw1,
                                             unsigned short* __restrict__ dw2,
                                             unsigned short* __restrict__ dw3)
{
    const float* s; unsigned short* d; size_t i;
    if (blockIdx.y < 3) {
        switch (blockIdx.y) {
            case 0:  s = x0; d = dx0; break;
            case 1:  s = x1; d = dx1; break;
            default: s = x2; d = dx2; break;
        }
        i = ((size_t)blockIdx.x * 256 + threadIdx.x) * 8;
    } else {
        if (blockIdx.x >= 512) return;
        switch (blockIdx.x >> 7) {
            case 0:  s = w0; d = dw0; break;
            case 1:  s = w1; d = dw1; break;
            case 2:  s = w2; d = dw2; break;
            default: s = w3; d = dw3; break;
        }
        i = ((size_t)(blockIdx.x & 127) * 256 + threadIdx.x) * 8;
    }
    *(short8*)(d + i) = pack8(s + i);
}

// ---------------------------------------------------------------------------
// Projections (all three in one launch, z selects q/k/v):
// C[m][f] = sum_d X[m][d]*W[f][d] + bias[f], scaled, written bf16.
// z<2: out[hb][s][dkv] (Q scaled by log2e/8, K); z==2: out[hb][dkv][s] (V^T).
// ---------------------------------------------------------------------------
__global__ __launch_bounds__(256, 4) void k_proj3(const unsigned short* __restrict__ Xq,
                                                  const unsigned short* __restrict__ Xk,
                                                  const unsigned short* __restrict__ Xv,
                                                  const unsigned short* __restrict__ Wq,
                                                  const unsigned short* __restrict__ Wk,
                                                  const unsigned short* __restrict__ Wv,
                                                  const float* __restrict__ bq,
                                                  const float* __restrict__ bk,
                                                  const float* __restrict__ bv,
                                                  unsigned short* __restrict__ oq,
                                                  unsigned short* __restrict__ ok,
                                                  unsigned short* __restrict__ ov)
{
    const unsigned short *X, *W; const float* bias; unsigned short* out;
    float scale = 1.0f; int vtrans = 0;
    switch (blockIdx.z) {
        case 0:  X = Xq; W = Wq; bias = bq; out = oq;
                 scale = 0.125f * 1.44269504088896340736f; break;
        case 1:  X = Xk; W = Wk; bias = bk; out = ok; break;
        default: X = Xv; W = Wv; bias = bv; out = ov; vtrans = 1; break;
    }
    const int tid = threadIdx.x;
    const int l = tid & 63, w = tid >> 6;
    const int c = l & 15, g = l >> 4;
    const int m0 = blockIdx.y * 64 + w * 16;
    const int f0 = blockIdx.x * 64;
    const int arow = m0 + c;

    f32x4 acc[4] = {};
    const unsigned short* aB = X + (size_t)arow * DM;
    for (int kb = 0; kb < DM; kb += 32) {
        short8 af = ld8(aB + kb + g * 8);
#pragma unroll
        for (int n = 0; n < 4; ++n) {
            short8 bf = ld8(W + (size_t)(f0 + n * 16 + c) * DM + kb + g * 8);
            acc[n] = mfma16(af, bf, acc[n]);
        }
    }
#pragma unroll
    for (int n = 0; n < 4; ++n) {
        const int f = f0 + n * 16 + c;
        const int h = f >> 6, d = f & 63;
        const float bvv = bias[f];
#pragma unroll
        for (int r = 0; r < 4; ++r) {
            const int m = m0 + g * 4 + r;
            const int bb = m >> 11, s = m & (NS - 1);
            const int hb = h * NB + bb;
            const float v = (acc[n][r] + bvv) * scale;
            const size_t idx = vtrans ? ((size_t)(hb * DKV + d) * NS + s)
                                      : ((size_t)(hb * NS + s) * DKV + d);
            out[idx] = f2bf(v);
        }
    }
}

// ---- K fragment load: 8 x dwordx4 into dst[4][2] -------------------------
#define LOADK(dst, kbase, k0)                                                 \
    do {                                                                      \
        _Pragma("unroll")                                                     \
        for (int t_ = 0; t_ < 4; ++t_) {                                      \
            const unsigned short* kp_ = (kbase) + (size_t)((k0) + t_ * 16 + c) * DKV + g * 8; \
            dst[t_][0] = ld8(kp_); dst[t_][1] = ld8(kp_ + 32);                \
        }                                                                     \
    } while (0)

// ---- V^T fragment load: 8 x dwordx4 into dst[2][4] -----------------------
#define LOADV(dst, vbase, k0)                                                 \
    do {                                                                      \
        _Pragma("unroll")                                                     \
        for (int kk_ = 0; kk_ < 2; ++kk_)                                     \
            _Pragma("unroll")                                                 \
            for (int n_ = 0; n_ < 4; ++n_)                                    \
                dst[kk_][n_] = ld8((vbase) + (size_t)(n_ * 16 + c) * NS + (k0) + kk_ * 32 + g * 8); \
    } while (0)

// ---------------------------------------------------------------------------
// Pass 1: partial softmax denominators. Barrier-free, zero LDS, K fragments
// direct from L2, double-buffered register prefetch (A/B) to hide latency.
// Key dim split in 2 (1024 keys/block); partials summed in k_att.
// ---------------------------------------------------------------------------
__global__ __launch_bounds__(256, 4) void k_sum(const unsigned short* __restrict__ Qh,
                                                const unsigned short* __restrict__ Kh,
                                                float* __restrict__ Lp)
{
    const int tid = threadIdx.x;
    const int l = tid & 63, w = tid >> 6;
    const int c = l & 15, g = l >> 4;

    // XCD swizzle: 2048 blocks = 8 XCDs x 256 (4 hb slices each)
    const int bid = blockIdx.x;
    const int wid = (bid & 7) * 256 + (bid >> 3);
    const int hb = wid >> 6;
    const int rem = wid & 63;
    const int q0 = (rem >> 1) * 64 + w * 16;       // this wave's 16 q-rows
    const int ks = rem & 1;                        // key half

    const unsigned short* qb = Qh + ((size_t)hb * NS + q0 + c) * DKV + g * 8;
    const short8 qf0 = ld8(qb), qf1 = ld8(qb + 32);
    const unsigned short* kslice = Kh + (size_t)hb * NS * DKV + (size_t)ks * 1024 * DKV;

    float ls[4] = {0.f, 0.f, 0.f, 0.f};
    short8 kfA[4][2], kfB[4][2];
    LOADK(kfA, kslice, 0);
#define SUM_STEP(kf)                                                          \
    do {                                                                      \
        _Pragma("unroll")                                                     \
        for (int t_ = 0; t_ < 4; ++t_) {                                      \
            f32x4 z_ = {};                                                    \
            z_ = mfma16(qf0, kf[t_][0], z_);                                  \
            z_ = mfma16(qf1, kf[t_][1], z_);                                  \
            _Pragma("unroll")                                                 \
            for (int r_ = 0; r_ < 4; ++r_) ls[r_] += exp2f(z_[r_]);           \
        }                                                                     \
    } while (0)
    for (int kt = 0; kt < 16; kt += 2) {
        LOADK(kfB, kslice, (kt + 1) * 64);
        __builtin_amdgcn_sched_barrier(0);
        SUM_STEP(kfA);
        if (kt + 2 < 16) LOADK(kfA, kslice, (kt + 2) * 64);
        __builtin_amdgcn_sched_barrier(0);
        SUM_STEP(kfB);
    }
#pragma unroll
    for (int r = 0; r < 4; ++r) {
        float s = ls[r];
        s += __shfl_xor(s, 1);
        s += __shfl_xor(s, 2);
        s += __shfl_xor(s, 4);
        s += __shfl_xor(s, 8);
        if (c == 0) Lp[(size_t)ks * HB * NS + hb * NS + q0 + g * 4 + r] = s;
    }
}

// ---------------------------------------------------------------------------
// Pass 2: barrier-free fused attention, double-buffered register prefetch of
// K and V fragments (A/B sets, 128 VGPRs of data in flight). Per-wave 2KB LDS
// transposes P (intra-wave lgkmcnt only). Writes normalized attn fp32 (wide
// f32x4 from LDS rows) and O bf16. launch_bounds(256,2) -> 256-VGPR budget.
// ---------------------------------------------------------------------------
__global__ __launch_bounds__(256, 2) void k_att(const unsigned short* __restrict__ Qh,
                                                const unsigned short* __restrict__ Kh,
                                                const unsigned short* __restrict__ Vt,
                                                const float* __restrict__ Lp,
                                                float* __restrict__ attn,
                                                unsigned short* __restrict__ Obuf)
{
    __shared__ __align__(16) char plds[4 * 2048];  // per-wave 16x64 bf16 P tile
    const int tid = threadIdx.x;
    const int l = tid & 63, w = tid >> 6;
    const int c = l & 15, g = l >> 4;
    constexpr int NT = NS / 64;

    // XCD swizzle: 1024 blocks = 8 XCDs x 128 (4 hb slices each)
    const int bid = blockIdx.x;
    const int wid = (bid & 7) * 128 + (bid >> 3);
    const int hb = wid >> 5;
    const int q0 = (wid & 31) * 64 + w * 16;       // this wave's 16 q-rows
    char* myp = plds + w * 2048;

    const unsigned short* kslice = Kh + (size_t)hb * NS * DKV;
    const unsigned short* vslice = Vt + (size_t)hb * DKV * NS;

    const unsigned short* qb = Qh + ((size_t)hb * NS + q0 + c) * DKV + g * 8;
    const short8 qf0 = ld8(qb), qf1 = ld8(qb + 32);

    float li[4];
#pragma unroll
    for (int r = 0; r < 4; ++r) {
        const size_t idx = (size_t)hb * NS + q0 + g * 4 + r;
        li[r] = 1.0f / (Lp[idx] + Lp[(size_t)HB * NS + idx]);
    }

    f32x4 oacc[4] = {};
    const int srow = l >> 2, sseg = l & 3;         // attn-store mapping
    float* srowp = attn + (size_t)hb * NS * NS + (size_t)(q0 + srow) * NS + sseg * 16;
    const int swsr = (srow & 7) << 4;
    const int swc = (c & 7) << 4;

#define ATT_STEP(k0, kf, vf)                                                  \
    do {                                                                      \
        f32x4 sc_[4];                                                         \
        _Pragma("unroll")                                                     \
        for (int t_ = 0; t_ < 4; ++t_) {                                      \
            f32x4 z_ = {};                                                    \
            z_ = mfma16(qf0, kf[t_][0], z_);                                  \
            z_ = mfma16(qf1, kf[t_][1], z_);                                  \
            sc_[t_] = z_;                                                     \
        }                                                                     \
        _Pragma("unroll")                                                     \
        for (int t_ = 0; t_ < 4; ++t_)                                        \
            _Pragma("unroll")                                                 \
            for (int r_ = 0; r_ < 4; ++r_) {                                  \
                const float p_ = exp2f(sc_[t_][r_]) * li[r_];                 \
                const int row_ = g * 4 + r_;                                  \
                int by_ = row_ * 128 + (t_ * 16 + c) * 2;                     \
                by_ ^= (row_ & 7) << 4;                                       \
                *(unsigned short*)(myp + by_) = f2bf(p_);                     \
            }                                                                 \
        asm volatile("s_waitcnt lgkmcnt(0)" ::: "memory");                    \
        __builtin_amdgcn_sched_barrier(0);                                    \
        {                                                                     \
            const short8 p0_ = *(const short8*)(myp + srow * 128 + ((sseg * 32) ^ swsr));      \
            const short8 p1_ = *(const short8*)(myp + srow * 128 + ((sseg * 32 + 16) ^ swsr)); \
            f32x4 o0_, o1_, o2_, o3_;                                         \
            _Pragma("unroll")                                                 \
            for (int j_ = 0; j_ < 4; ++j_) {                                  \
                o0_[j_] = bf2f((unsigned short)p0_[j_]);                      \
                o1_[j_] = bf2f((unsigned short)p0_[4 + j_]);                  \
                o2_[j_] = bf2f((unsigned short)p1_[j_]);                      \
                o3_[j_] = bf2f((unsigned short)p1_[4 + j_]);                  \
            }                                                                 \
            float* dst_ = srowp + (k0);                                       \
            *(f32x4*)(dst_)      = o0_;                                       \
            *(f32x4*)(dst_ + 4)  = o1_;                                       \
            *(f32x4*)(dst_ + 8)  = o2_;                                       \
            *(f32x4*)(dst_ + 12) = o3_;                                       \
        }                                                                     \
        _Pragma("unroll")                                                     \
        for (int kk_ = 0; kk_ < 2; ++kk_) {                                   \
            const short8 pa_ = *(const short8*)(myp + c * 128 + ((kk_ * 64 + g * 16) ^ swc));  \
            _Pragma("unroll")                                                 \
            for (int n_ = 0; n_ < 4; ++n_)                                    \
                oacc[n_] = mfma16(pa_, vf[kk_][n_], oacc[n_]);                \
        }                                                                     \
    } while (0)

    short8 kfA[4][2], vfA[2][4], kfB[4][2], vfB[2][4];
    LOADK(kfA, kslice, 0);
    LOADV(vfA, vslice, 0);
    for (int kt = 0; kt < NT; kt += 2) {
        // prefetch kt+1 into B while computing kt from A
        LOADK(kfB, kslice, (kt + 1) * 64);
        LOADV(vfB, vslice, (kt + 1) * 64);
        __builtin_amdgcn_sched_barrier(0);
        ATT_STEP(kt * 64, kfA, vfA);
        // prefetch kt+2 into A while computing kt+1 from B
        if (kt + 2 < NT) {
            LOADK(kfA, kslice, (kt + 2) * 64);
            LOADV(vfA, vslice, (kt + 2) * 64);
        }
        __builtin_amdgcn_sched_barrier(0);
        ATT_STEP((kt + 1) * 64, kfB, vfB);
    }

    const int h = hb >> 2, bb = hb & 3;
#pragma unroll
    for (int n = 0; n < 4; ++n)
#pragma unroll
        for (int r = 0; r < 4; ++r) {
            const int q = q0 + g * 4 + r;
            const int dv = n * 16 + c;
            Obuf[((size_t)(bb * NS + q)) * DM + h * DKV + dv] = f2bf(oacc[n][r]);
        }
}

// ---------------------------------------------------------------------------
// FC: Y[m][d] = sum_f O[m][f]*Wfc[d][f] + bfc[d] + resid[m][d], bf16 out.
// ---------------------------------------------------------------------------
__global__ __launch_bounds__(256, 4) void k_fc(const unsigned short* __restrict__ O,
                                            const unsigned short* __restrict__ Wfc,
                                            const float* __restrict__ bfc,
                                            const float* __restrict__ resid,
                                            unsigned short* __restrict__ Y)
{
    const int tid = threadIdx.x;
    const int l = tid & 63, w = tid >> 6;
    const int c = l & 15, g = l >> 4;
    const int m0 = blockIdx.y * 64 + w * 16;
    const int f0 = blockIdx.x * 64;
    const int arow = m0 + c;

    f32x4 acc[4] = {};
    const unsigned short* aB = O + (size_t)arow * DM;
    for (int kb = 0; kb < DM; kb += 32) {
        short8 af = ld8(aB + kb + g * 8);
#pragma unroll
        for (int n = 0; n < 4; ++n) {
            short8 bf = ld8(Wfc + (size_t)(f0 + n * 16 + c) * DM + kb + g * 8);
            acc[n] = mfma16(af, bf, acc[n]);
        }
    }
#pragma unroll
    for (int n = 0; n < 4; ++n) {
        const int d = f0 + n * 16 + c;
        const float bv = bfc[d];
#pragma unroll
        for (int r = 0; r < 4; ++r) {
            const int m = m0 + g * 4 + r;
            const float v = acc[n][r] + bv + resid[(size_t)m * DM + d];
            Y[(size_t)m * DM + d] = f2bf(v);
        }
    }
}

// ---------------------------------------------------------------------------
// LayerNorm: one wave per row of 512.
// ---------------------------------------------------------------------------
__global__ __launch_bounds__(256) void k_ln(const unsigned short* __restrict__ Y,
                                            const float* __restrict__ gam,
                                            const float* __restrict__ bet,
                                            float* __restrict__ out)
{
    const int tid = threadIdx.x;
    const int l = tid & 63, w = tid >> 6;
    const int row = blockIdx.x * 4 + w;

    const short8 yv = ld8(Y + (size_t)row * DM + l * 8);
    float x[8];
#pragma unroll
    for (int j = 0; j < 8; ++j) x[j] = bf2f((unsigned short)yv[j]);

    float s = 0.f;
#pragma unroll
    for (int j = 0; j < 8; ++j) s += x[j];
#pragma unroll
    for (int mask = 1; mask <= 32; mask <<= 1) s += __shfl_xor(s, mask);
    const float mean = s * (1.0f / DM);

    float d2 = 0.f;
#pragma unroll
    for (int j = 0; j < 8; ++j) { const float t = x[j] - mean; d2 += t * t; }
#pragma unroll
    for (int mask = 1; mask <= 32; mask <<= 1) d2 += __shfl_xor(d2, mask);
    const float rstd = rsqrtf(d2 * (1.0f / DM) + 1e-5f);

#pragma unroll
    for (int j = 0; j < 8; ++j) {
        const int d = l * 8 + j;
        out[(size_t)row * DM + d] = (x[j] - mean) * rstd * gam[d] + bet[d];
    }
}

// ---------------------------------------------------------------------------
extern "C" void kernel_launch(void* const* d_in, const int* in_sizes, int n_in,
                              void* d_out, int out_size, void* d_ws, size_t ws_size,
                              hipStream_t stream)
{
    const float* q    = (const float*)d_in[0];
    const float* k    = (const float*)d_in[1];
    const float* v    = (const float*)d_in[2];
    const float* w_qs = (const float*)d_in[3];
    const float* b_qs = (const float*)d_in[4];
    const float* w_ks = (const float*)d_in[5];
    const float* b_ks = (const float*)d_in[6];
    const float* w_vs = (const float*)d_in[7];
    const float* b_vs = (const float*)d_in[8];
    const float* w_fc = (const float*)d_in[9];
    const float* b_fc = (const float*)d_in[10];
    const float* ln_g = (const float*)d_in[11];
    const float* ln_b = (const float*)d_in[12];

    char* ws = (char*)d_ws;
    unsigned short* Qh = (unsigned short*)(ws);                    //  8 MB bf16 [hb][s][64], scaled log2e/8
    unsigned short* Kh = (unsigned short*)(ws + (8u  << 20));      //  8 MB bf16 [hb][s][64]
    unsigned short* Vt = (unsigned short*)(ws + (16u << 20));      //  8 MB bf16 [hb][64][s]
    unsigned short* Ob = (unsigned short*)(ws + (24u << 20));      //  8 MB bf16 [m][512]
    unsigned short* Yb = (unsigned short*)(ws + (32u << 20));      //  8 MB bf16 [m][512]
    unsigned short* Wq = (unsigned short*)(ws + (40u << 20));      // 512 KB bf16 each
    unsigned short* Wk = Wq + (size_t)DM * DM;
    unsigned short* Wv = Wk + (size_t)DM * DM;
    unsigned short* Wf = Wv + (size_t)DM * DM;
    unsigned short* Xq = (unsigned short*)(ws + (48u << 20));      //  8 MB bf16 each
    unsigned short* Xk = (unsigned short*)(ws + (56u << 20));
    unsigned short* Xv = (unsigned short*)(ws + (64u << 20));
    float*          Lpart = (float*)(ws + (72u << 20));            // 2 x 256 KB partial denoms

    float* xout = (float*)d_out;
    float* attn = xout + (size_t)NB * NS * DM;  // output 1 region

    k_cvt<<<dim3(2048, 4), 256, 0, stream>>>(q, k, v, w_qs, w_ks, w_vs, w_fc,
                                             Xq, Xk, Xv, Wq, Wk, Wv, Wf);

    k_proj3<<<dim3(8, 128, 3), 256, 0, stream>>>(Xq, Xk, Xv, Wq, Wk, Wv,
                                                 b_qs, b_ks, b_vs, Qh, Kh, Vt);

    k_sum<<<2048, 256, 0, stream>>>(Qh, Kh, Lpart);
    k_att<<<1024, 256, 0, stream>>>(Qh, Kh, Vt, Lpart, attn, Ob);

    k_fc<<<dim3(8, 128), 256, 0, stream>>>(Ob, Wf, b_fc, q, Yb);
    k_ln<<<NB * NS / 4, 256, 0, stream>>>(Yb, ln_g, ln_b, xout);
}

// Round 9
// 450.833 us; speedup vs baseline: 1.8208x; 1.8208x over previous
//
#include <hip/hip_runtime.h>
#include <hip/hip_bf16.h>

// Problem constants
constexpr int NB  = 4;     // batch
constexpr int NS  = 2048;  // sequence
constexpr int NH  = 8;     // heads
constexpr int DM  = 512;   // d_model
constexpr int DKV = 64;    // d_k = d_v
constexpr int HB  = NH * NB; // 32 (h,b) slices

typedef __attribute__((ext_vector_type(8))) short short8;
typedef __attribute__((ext_vector_type(4))) float f32x4;

__device__ inline unsigned short f2bf(float f) {
    unsigned u = __builtin_bit_cast(unsigned, f);
    u = (u + 0x7fffu + ((u >> 16) & 1u)) >> 16;   // RNE, finite inputs
    return (unsigned short)u;
}
__device__ inline float bf2f(unsigned short h) {
    unsigned u = ((unsigned)h) << 16;
    return __builtin_bit_cast(float, u);
}
__device__ inline short8 ld8(const unsigned short* p) { return *(const short8*)p; }

// Load 8 consecutive fp32, convert to bf16x8 fragment
__device__ inline short8 pack8(const float* p) {
    f32x4 a = *(const f32x4*)p;
    f32x4 b = *(const f32x4*)(p + 4);
    short8 r;
    r[0] = (short)f2bf(a[0]); r[1] = (short)f2bf(a[1]);
    r[2] = (short)f2bf(a[2]); r[3] = (short)f2bf(a[3]);
    r[4] = (short)f2bf(b[0]); r[5] = (short)f2bf(b[1]);
    r[6] = (short)f2bf(b[2]); r[7] = (short)f2bf(b[3]);
    return r;
}

__device__ inline f32x4 mfma16(short8 a, short8 b, f32x4 c) {
    return __builtin_amdgcn_mfma_f32_16x16x32_bf16(a, b, c, 0, 0, 0);
}

// async global->LDS, 16 bytes per lane; lds base must be wave-uniform
__device__ inline void gl_lds16(const void* g, void* l) {
    __builtin_amdgcn_global_load_lds(
        (const __attribute__((address_space(1))) unsigned*)g,
        (__attribute__((address_space(3))) unsigned*)l, 16, 0, 0);
}

__device__ inline void bar() { __builtin_amdgcn_s_barrier(); }

// ---------------------------------------------------------------------------
// Convert the four 512x512 fp32 weight matrices to bf16. grid (128, 4).
// ---------------------------------------------------------------------------
__global__ __launch_bounds__(256) void k_cvtw(const float* __restrict__ s0,
                                              const float* __restrict__ s1,
                                              const float* __restrict__ s2,
                                              const float* __restrict__ s3,
                                              unsigned short* __restrict__ d0,
                                              unsigned short* __restrict__ d1,
                                              unsigned short* __restrict__ d2,
                                              unsigned short* __restrict__ d3)
{
    const float* s; unsigned short* d;
    switch (blockIdx.y) {
        case 0:  s = s0; d = d0; break;
        case 1:  s = s1; d = d1; break;
        case 2:  s = s2; d = d2; break;
        default: s = s3; d = d3; break;
    }
    const size_t i = ((size_t)blockIdx.x * 256 + threadIdx.x) * 8;
    *(short8*)(d + i) = pack8(s + i);
}

// ---------------------------------------------------------------------------
// Projections (all three in one launch, z selects q/k/v). X is fp32 (packed
// to bf16 in-loop), W pre-converted bf16.
// z<2: out[hb][s][dkv] (Q scaled by log2e/8, K); z==2: out[hb][dkv][s] (V^T).
// ---------------------------------------------------------------------------
__global__ __launch_bounds__(256, 4) void k_proj3(const float* __restrict__ Xq,
                                                  const float* __restrict__ Xk,
                                                  const float* __restrict__ Xv,
                                                  const unsigned short* __restrict__ Wq,
                                                  const unsigned short* __restrict__ Wk,
                                                  const unsigned short* __restrict__ Wv,
                                                  const float* __restrict__ bq,
                                                  const float* __restrict__ bk,
                                                  const float* __restrict__ bv,
                                                  unsigned short* __restrict__ oq,
                                                  unsigned short* __restrict__ ok,
                                                  unsigned short* __restrict__ ov)
{
    const float* X; const unsigned short* W; const float* bias; unsigned short* out;
    float scale = 1.0f; int vtrans = 0;
    switch (blockIdx.z) {
        case 0:  X = Xq; W = Wq; bias = bq; out = oq;
                 scale = 0.125f * 1.44269504088896340736f; break;
        case 1:  X = Xk; W = Wk; bias = bk; out = ok; break;
        default: X = Xv; W = Wv; bias = bv; out = ov; vtrans = 1; break;
    }
    const int tid = threadIdx.x;
    const int l = tid & 63, w = tid >> 6;
    const int c = l & 15, g = l >> 4;
    const int m0 = blockIdx.y * 64 + w * 16;
    const int f0 = blockIdx.x * 64;
    const int arow = m0 + c;

    f32x4 acc[4] = {};
    const float* aB = X + (size_t)arow * DM;
    for (int kb = 0; kb < DM; kb += 32) {
        short8 af = pack8(aB + kb + g * 8);
#pragma unroll
        for (int n = 0; n < 4; ++n) {
            short8 bf = ld8(W + (size_t)(f0 + n * 16 + c) * DM + kb + g * 8);
            acc[n] = mfma16(af, bf, acc[n]);
        }
    }
#pragma unroll
    for (int n = 0; n < 4; ++n) {
        const int f = f0 + n * 16 + c;
        const int h = f >> 6, d = f & 63;
        const float bvv = bias[f];
#pragma unroll
        for (int r = 0; r < 4; ++r) {
            const int m = m0 + g * 4 + r;
            const int bb = m >> 11, s = m & (NS - 1);
            const int hb = h * NB + bb;
            const float v = (acc[n][r] + bvv) * scale;
            const size_t idx = vtrans ? ((size_t)(hb * DKV + d) * NS + s)
                                      : ((size_t)(hb * NS + s) * DKV + d);
            out[idx] = f2bf(v);
        }
    }
}

// ---------------------------------------------------------------------------
// Fused attention (R6 structure, verified 428us total), double-buffered K/V
// staging, 2-barrier schedule with counted vmcnt (never waits on stores).
// Pass 1: l = sum(exp2(s)); pass 2: normalized P -> swizzled per-wave LDS,
// wide f32x4 attn stores, PV from LDS. XCD-chunked block swizzle.
// s_setprio(1) around MFMA clusters (T5).
// ---------------------------------------------------------------------------
__global__ __launch_bounds__(256, 4) void k_attn(const unsigned short* __restrict__ Qh,
                                                 const unsigned short* __restrict__ Kh,
                                                 const unsigned short* __restrict__ Vt,
                                                 float* __restrict__ attn,
                                                 unsigned short* __restrict__ Obuf)
{
    __shared__ __align__(16) char kld[2][8192];    // 64 keys x 64 dims bf16 (swizzled)
    __shared__ __align__(16) char vld[2][8192];    // 64 dims x 64 keys bf16 (swizzled)
    __shared__ __align__(16) char plds[4 * 2048];  // per-wave 16x64 bf16 P tile
    const int tid = threadIdx.x;
    const int l = tid & 63, w = tid >> 6;
    const int c = l & 15, g = l >> 4;
    constexpr int NT = NS / 64;                    // 32 key tiles

    // XCD-chunked swizzle: 1024 blocks, 8 XCDs -> 128 consecutive work-ids
    // (4 full hb slices) per XCD.
    const int bid = blockIdx.x;
    const int wid = (bid & 7) * 128 + (bid >> 3);
    const int hb = wid >> 5;
    const int q0 = (wid & 31) * 64 + w * 16;       // this wave's 16 q-rows
    char* myp = plds + w * 2048;

    const char* kbytes = (const char*)(Kh + (size_t)hb * NS * DKV);
    const char* vbytes = (const char*)(Vt + (size_t)hb * DKV * NS);

    const unsigned short* qb = Qh + ((size_t)hb * NS + q0 + c) * DKV + g * 8;
    const short8 qf0 = ld8(qb), qf1 = ld8(qb + 32);

    // staging source offsets (pre-swizzled): issue j covers LDS chunk
    // (w*2+j)*1024 + lane*16; row = chunk_row + (lane>>3), colb = (lane&7)*16.
    int koff[2], voff[2];
#pragma unroll
    for (int j = 0; j < 2; ++j) {
        const int D = (w * 2 + j) * 1024 + l * 16;
        const int row = D >> 7;
        const int scolb = (D & 127) ^ ((row & 7) << 4);
        koff[j] = row * 128 + scolb;               // K rows: 128 B stride in tile
        voff[j] = row * (NS * 2) + scolb;          // V^T rows: 4096 B global stride
    }
    const int swc = (c & 7) << 4;                  // read-side swizzle

    const int ldsbase = w * 2048;                  // this wave's chunk base

    // ---- pass 1: row sums of exp2(s), K double-buffered
    float ls[4] = {0.f, 0.f, 0.f, 0.f};
    {
        gl_lds16(kbytes + koff[0], kld[0] + ldsbase);
        gl_lds16(kbytes + koff[1], kld[0] + ldsbase + 1024);
        asm volatile("s_waitcnt vmcnt(0)" ::: "memory");
        bar();                                     // publish tile 0
        __builtin_amdgcn_sched_barrier(0);
        int cur = 0;
        for (int kt = 0; kt < NT; ++kt) {
            if (kt + 1 < NT) {
                const size_t nb = (size_t)(kt + 1) * 64 * 128;
                gl_lds16(kbytes + nb + koff[0], kld[cur ^ 1] + ldsbase);
                gl_lds16(kbytes + nb + koff[1], kld[cur ^ 1] + ldsbase + 1024);
            }
            if (kt > 0) {
                if (kt + 1 < NT) { asm volatile("s_waitcnt vmcnt(2)" ::: "memory"); }
                else             { asm volatile("s_waitcnt vmcnt(0)" ::: "memory"); }
                bar();                             // publish tile kt
                __builtin_amdgcn_sched_barrier(0);
            }
            __builtin_amdgcn_s_setprio(1);
#pragma unroll
            for (int t = 0; t < 4; ++t) {
                const int rb = (t * 16 + c) * 128;
                const short8 b0 = *(const short8*)(kld[cur] + rb + ((g * 16) ^ swc));
                const short8 b1 = *(const short8*)(kld[cur] + rb + ((64 + g * 16) ^ swc));
                f32x4 z = {};
                z = mfma16(qf0, b0, z);
                z = mfma16(qf1, b1, z);
#pragma unroll
                for (int r = 0; r < 4; ++r) ls[r] += exp2f(z[r]);
            }
            __builtin_amdgcn_s_setprio(0);
            bar();                                 // release kld[cur] for overwrite
            cur ^= 1;
        }
    }
    float li[4];
#pragma unroll
    for (int r = 0; r < 4; ++r) {
        float s = ls[r];
        s += __shfl_xor(s, 1);
        s += __shfl_xor(s, 2);
        s += __shfl_xor(s, 4);
        s += __shfl_xor(s, 8);
        li[r] = 1.0f / s;
    }

    // ---- pass 2
    f32x4 oacc[4] = {};
    const int srow = l >> 2, sseg = l & 3;         // attn-store mapping (16 rows)
    float* srowp = attn + (size_t)hb * NS * NS + (size_t)(q0 + srow) * NS + sseg * 16;
    const int swsr = (srow & 7) << 4;

    {
        gl_lds16(kbytes + koff[0], kld[0] + ldsbase);
        gl_lds16(kbytes + koff[1], kld[0] + ldsbase + 1024);
        gl_lds16(vbytes + voff[0], vld[0] + ldsbase);
        gl_lds16(vbytes + voff[1], vld[0] + ldsbase + 1024);
        asm volatile("s_waitcnt vmcnt(0)" ::: "memory");
        bar();                                     // publish tile 0
        __builtin_amdgcn_sched_barrier(0);
        int cur = 0;
        for (int kt = 0; kt < NT; ++kt) {
            const int k0 = kt * 64;
            if (kt + 1 < NT) {
                const size_t nkb = (size_t)(k0 + 64) * 128;
                const size_t nvb = (size_t)(k0 + 64) * 2;
                gl_lds16(kbytes + nkb + koff[0], kld[cur ^ 1] + ldsbase);
                gl_lds16(kbytes + nkb + koff[1], kld[cur ^ 1] + ldsbase + 1024);
                gl_lds16(vbytes + nvb + voff[0], vld[cur ^ 1] + ldsbase);
                gl_lds16(vbytes + nvb + voff[1], vld[cur ^ 1] + ldsbase + 1024);
            }
            if (kt > 0) {
                // queue (old->new): L_kt(4), S_{kt-1}(4), L_{kt+1}(4).
                // vmcnt(8) drains L_kt only; never waits on stores.
                if (kt + 1 < NT) { asm volatile("s_waitcnt vmcnt(8)" ::: "memory"); }
                else             { asm volatile("s_waitcnt vmcnt(4)" ::: "memory"); }
                bar();                             // publish tile kt
                __builtin_amdgcn_sched_barrier(0);
            }
            // QK^T from K-LDS
            f32x4 sc[4];
            __builtin_amdgcn_s_setprio(1);
#pragma unroll
            for (int t = 0; t < 4; ++t) {
                const int rb = (t * 16 + c) * 128;
                const short8 b0 = *(const short8*)(kld[cur] + rb + ((g * 16) ^ swc));
                const short8 b1 = *(const short8*)(kld[cur] + rb + ((64 + g * 16) ^ swc));
                f32x4 z = {};
                z = mfma16(qf0, b0, z);
                z = mfma16(qf1, b1, z);
                sc[t] = z;
            }
            __builtin_amdgcn_s_setprio(0);
            // normalized P -> swizzled per-wave LDS (bf16)
#pragma unroll
            for (int t = 0; t < 4; ++t)
#pragma unroll
                for (int r = 0; r < 4; ++r) {
                    const float p = exp2f(sc[t][r]) * li[r];
                    const int row = g * 4 + r;
                    int by = row * 128 + (t * 16 + c) * 2;
                    by ^= (row & 7) << 4;
                    *(unsigned short*)(myp + by) = f2bf(p);
                }
            asm volatile("s_waitcnt lgkmcnt(0)" ::: "memory");
            __builtin_amdgcn_sched_barrier(0);
            // attn store (plain f32x4; retires under the PV MFMA block)
            {
                const short8 p0 = *(const short8*)(myp + srow * 128 + ((sseg * 32) ^ swsr));
                const short8 p1 = *(const short8*)(myp + srow * 128 + ((sseg * 32 + 16) ^ swsr));
                f32x4 o0, o1, o2, o3;
#pragma unroll
                for (int j = 0; j < 4; ++j) {
                    o0[j] = bf2f((unsigned short)p0[j]);
                    o1[j] = bf2f((unsigned short)p0[4 + j]);
                    o2[j] = bf2f((unsigned short)p1[j]);
                    o3[j] = bf2f((unsigned short)p1[4 + j]);
                }
                float* dst = srowp + k0;
                *(f32x4*)(dst)      = o0;
                *(f32x4*)(dst + 4)  = o1;
                *(f32x4*)(dst + 8)  = o2;
                *(f32x4*)(dst + 12) = o3;
            }
            // PV: A-frags of P from wave LDS, B-frags of V^T from block LDS
            __builtin_amdgcn_s_setprio(1);
#pragma unroll
            for (int kk = 0; kk < 2; ++kk) {
                const short8 pa = *(const short8*)(myp + c * 128 + ((kk * 64 + g * 16) ^ swc));
#pragma unroll
                for (int n = 0; n < 4; ++n) {
                    const int rb = (n * 16 + c) * 128;
                    const short8 vb = *(const short8*)(vld[cur] + rb + ((kk * 64 + g * 16) ^ swc));
                    oacc[n] = mfma16(pa, vb, oacc[n]);
                }
            }
            __builtin_amdgcn_s_setprio(0);
            bar();                                 // release buf[cur] for overwrite
            cur ^= 1;
        }
    }

    const int h = hb >> 2, bb = hb & 3;
#pragma unroll
    for (int n = 0; n < 4; ++n)
#pragma unroll
        for (int r = 0; r < 4; ++r) {
            const int q = q0 + g * 4 + r;
            const int dv = n * 16 + c;
            Obuf[((size_t)(bb * NS + q)) * DM + h * DKV + dv] = f2bf(oacc[n][r]);
        }
}

// ---------------------------------------------------------------------------
// FC: Y[m][d] = sum_f O[m][f]*Wfc[d][f] + bfc[d] + resid[m][d], bf16 out.
// ---------------------------------------------------------------------------
__global__ __launch_bounds__(256, 4) void k_fc(const unsigned short* __restrict__ O,
                                            const unsigned short* __restrict__ Wfc,
                                            const float* __restrict__ bfc,
                                            const float* __restrict__ resid,
                                            unsigned short* __restrict__ Y)
{
    const int tid = threadIdx.x;
    const int l = tid & 63, w = tid >> 6;
    const int c = l & 15, g = l >> 4;
    const int m0 = blockIdx.y * 64 + w * 16;
    const int f0 = blockIdx.x * 64;
    const int arow = m0 + c;

    f32x4 acc[4] = {};
    const unsigned short* aB = O + (size_t)arow * DM;
    for (int kb = 0; kb < DM; kb += 32) {
        short8 af = ld8(aB + kb + g * 8);
#pragma unroll
        for (int n = 0; n < 4; ++n) {
            short8 bf = ld8(Wfc + (size_t)(f0 + n * 16 + c) * DM + kb + g * 8);
            acc[n] = mfma16(af, bf, acc[n]);
        }
    }
#pragma unroll
    for (int n = 0; n < 4; ++n) {
        const int d = f0 + n * 16 + c;
        const float bv = bfc[d];
#pragma unroll
        for (int r = 0; r < 4; ++r) {
            const int m = m0 + g * 4 + r;
            const float v = acc[n][r] + bv + resid[(size_t)m * DM + d];
            Y[(size_t)m * DM + d] = f2bf(v);
        }
    }
}

// ---------------------------------------------------------------------------
// LayerNorm: one wave per row of 512.
// ---------------------------------------------------------------------------
__global__ __launch_bounds__(256) void k_ln(const unsigned short* __restrict__ Y,
                                            const float* __restrict__ gam,
                                            const float* __restrict__ bet,
                                            float* __restrict__ out)
{
    const int tid = threadIdx.x;
    const int l = tid & 63, w = tid >> 6;
    const int row = blockIdx.x * 4 + w;

    const short8 yv = ld8(Y + (size_t)row * DM + l * 8);
    float x[8];
#pragma unroll
    for (int j = 0; j < 8; ++j) x[j] = bf2f((unsigned short)yv[j]);

    float s = 0.f;
#pragma unroll
    for (int j = 0; j < 8; ++j) s += x[j];
#pragma unroll
    for (int mask = 1; mask <= 32; mask <<= 1) s += __shfl_xor(s, mask);
    const float mean = s * (1.0f / DM);

    float d2 = 0.f;
#pragma unroll
    for (int j = 0; j < 8; ++j) { const float t = x[j] - mean; d2 += t * t; }
#pragma unroll
    for (int mask = 1; mask <= 32; mask <<= 1) d2 += __shfl_xor(d2, mask);
    const float rstd = rsqrtf(d2 * (1.0f / DM) + 1e-5f);

#pragma unroll
    for (int j = 0; j < 8; ++j) {
        const int d = l * 8 + j;
        out[(size_t)row * DM + d] = (x[j] - mean) * rstd * gam[d] + bet[d];
    }
}

// ---------------------------------------------------------------------------
extern "C" void kernel_launch(void* const* d_in, const int* in_sizes, int n_in,
                              void* d_out, int out_size, void* d_ws, size_t ws_size,
                              hipStream_t stream)
{
    const float* q    = (const float*)d_in[0];
    const float* k    = (const float*)d_in[1];
    const float* v    = (const float*)d_in[2];
    const float* w_qs = (const float*)d_in[3];
    const float* b_qs = (const float*)d_in[4];
    const float* w_ks = (const float*)d_in[5];
    const float* b_ks = (const float*)d_in[6];
    const float* w_vs = (const float*)d_in[7];
    const float* b_vs = (const float*)d_in[8];
    const float* w_fc = (const float*)d_in[9];
    const float* b_fc = (const float*)d_in[10];
    const float* ln_g = (const float*)d_in[11];
    const float* ln_b = (const float*)d_in[12];

    char* ws = (char*)d_ws;
    unsigned short* Qh = (unsigned short*)(ws);                    //  8 MB bf16 [hb][s][64], scaled log2e/8
    unsigned short* Kh = (unsigned short*)(ws + (8u  << 20));      //  8 MB bf16 [hb][s][64]
    unsigned short* Vt = (unsigned short*)(ws + (16u << 20));      //  8 MB bf16 [hb][64][s]
    unsigned short* Ob = (unsigned short*)(ws + (24u << 20));      //  8 MB bf16 [m][512]
    unsigned short* Yb = (unsigned short*)(ws + (32u << 20));      //  8 MB bf16 [m][512]
    unsigned short* Wq = (unsigned short*)(ws + (40u << 20));      // 512 KB bf16 each
    unsigned short* Wk = Wq + (size_t)DM * DM;
    unsigned short* Wv = Wk + (size_t)DM * DM;
    unsigned short* Wf = Wv + (size_t)DM * DM;

    float* xout = (float*)d_out;
    float* attn = xout + (size_t)NB * NS * DM;  // output 1 region

    k_cvtw<<<dim3(128, 4), 256, 0, stream>>>(w_qs, w_ks, w_vs, w_fc, Wq, Wk, Wv, Wf);

    k_proj3<<<dim3(8, 128, 3), 256, 0, stream>>>(q, k, v, Wq, Wk, Wv,
                                                 b_qs, b_ks, b_vs, Qh, Kh, Vt);

    k_attn<<<1024, 256, 0, stream>>>(Qh, Kh, Vt, attn, Ob);

    k_fc<<<dim3(8, 128), 256, 0, stream>>>(Ob, Wf, b_fc, q, Yb);
    k_ln<<<NB * NS / 4, 256, 0, stream>>>(Yb, ln_g, ln_b, xout);
}

// Round 10
// 399.802 us; speedup vs baseline: 2.0533x; 1.1276x over previous
//
#include <hip/hip_runtime.h>
#include <hip/hip_bf16.h>

// Problem constants
constexpr int NB  = 4;     // batch
constexpr int NS  = 2048;  // sequence
constexpr int NH  = 8;     // heads
constexpr int DM  = 512;   // d_model
constexpr int DKV = 64;    // d_k = d_v
constexpr int HB  = NH * NB; // 32 (h,b) slices

typedef __attribute__((ext_vector_type(8))) short short8;
typedef __attribute__((ext_vector_type(4))) float f32x4;

__device__ inline unsigned short f2bf(float f) {
    unsigned u = __builtin_bit_cast(unsigned, f);
    u = (u + 0x7fffu + ((u >> 16) & 1u)) >> 16;   // RNE, finite inputs
    return (unsigned short)u;
}
__device__ inline float bf2f(unsigned short h) {
    unsigned u = ((unsigned)h) << 16;
    return __builtin_bit_cast(float, u);
}
__device__ inline short8 ld8(const unsigned short* p) { return *(const short8*)p; }

// Load 8 consecutive fp32, convert to bf16x8 fragment
__device__ inline short8 pack8(const float* p) {
    f32x4 a = *(const f32x4*)p;
    f32x4 b = *(const f32x4*)(p + 4);
    short8 r;
    r[0] = (short)f2bf(a[0]); r[1] = (short)f2bf(a[1]);
    r[2] = (short)f2bf(a[2]); r[3] = (short)f2bf(a[3]);
    r[4] = (short)f2bf(b[0]); r[5] = (short)f2bf(b[1]);
    r[6] = (short)f2bf(b[2]); r[7] = (short)f2bf(b[3]);
    return r;
}

__device__ inline f32x4 mfma16(short8 a, short8 b, f32x4 c) {
    return __builtin_amdgcn_mfma_f32_16x16x32_bf16(a, b, c, 0, 0, 0);
}

// async global->LDS, 16 bytes per lane; lds base must be wave-uniform
__device__ inline void gl_lds16(const void* g, void* l) {
    __builtin_amdgcn_global_load_lds(
        (const __attribute__((address_space(1))) unsigned*)g,
        (__attribute__((address_space(3))) unsigned*)l, 16, 0, 0);
}

__device__ inline void bar() { __builtin_amdgcn_s_barrier(); }

// ---------------------------------------------------------------------------
// Convert the four 512x512 fp32 weight matrices to bf16. grid (128, 4).
// ---------------------------------------------------------------------------
__global__ __launch_bounds__(256) void k_cvtw(const float* __restrict__ s0,
                                              const float* __restrict__ s1,
                                              const float* __restrict__ s2,
                                              const float* __restrict__ s3,
                                              unsigned short* __restrict__ d0,
                                              unsigned short* __restrict__ d1,
                                              unsigned short* __restrict__ d2,
                                              unsigned short* __restrict__ d3)
{
    const float* s; unsigned short* d;
    switch (blockIdx.y) {
        case 0:  s = s0; d = d0; break;
        case 1:  s = s1; d = d1; break;
        case 2:  s = s2; d = d2; break;
        default: s = s3; d = d3; break;
    }
    const size_t i = ((size_t)blockIdx.x * 256 + threadIdx.x) * 8;
    *(short8*)(d + i) = pack8(s + i);
}

// ---------------------------------------------------------------------------
// Projections (all three in one launch, z selects q/k/v). X is fp32 (packed
// to bf16 in-loop), W pre-converted bf16.
// z<2: out[hb][s][dkv] (Q scaled by log2e/8, K); z==2: out[hb][dkv][s] (V^T).
// ---------------------------------------------------------------------------
__global__ __launch_bounds__(256, 4) void k_proj3(const float* __restrict__ Xq,
                                                  const float* __restrict__ Xk,
                                                  const float* __restrict__ Xv,
                                                  const unsigned short* __restrict__ Wq,
                                                  const unsigned short* __restrict__ Wk,
                                                  const unsigned short* __restrict__ Wv,
                                                  const float* __restrict__ bq,
                                                  const float* __restrict__ bk,
                                                  const float* __restrict__ bv,
                                                  unsigned short* __restrict__ oq,
                                                  unsigned short* __restrict__ ok,
                                                  unsigned short* __restrict__ ov)
{
    const float* X; const unsigned short* W; const float* bias; unsigned short* out;
    float scale = 1.0f; int vtrans = 0;
    switch (blockIdx.z) {
        case 0:  X = Xq; W = Wq; bias = bq; out = oq;
                 scale = 0.125f * 1.44269504088896340736f; break;
        case 1:  X = Xk; W = Wk; bias = bk; out = ok; break;
        default: X = Xv; W = Wv; bias = bv; out = ov; vtrans = 1; break;
    }
    const int tid = threadIdx.x;
    const int l = tid & 63, w = tid >> 6;
    const int c = l & 15, g = l >> 4;
    const int m0 = blockIdx.y * 64 + w * 16;
    const int f0 = blockIdx.x * 64;
    const int arow = m0 + c;

    f32x4 acc[4] = {};
    const float* aB = X + (size_t)arow * DM;
    for (int kb = 0; kb < DM; kb += 32) {
        short8 af = pack8(aB + kb + g * 8);
#pragma unroll
        for (int n = 0; n < 4; ++n) {
            short8 bf = ld8(W + (size_t)(f0 + n * 16 + c) * DM + kb + g * 8);
            acc[n] = mfma16(af, bf, acc[n]);
        }
    }
#pragma unroll
    for (int n = 0; n < 4; ++n) {
        const int f = f0 + n * 16 + c;
        const int h = f >> 6, d = f & 63;
        const float bvv = bias[f];
#pragma unroll
        for (int r = 0; r < 4; ++r) {
            const int m = m0 + g * 4 + r;
            const int bb = m >> 11, s = m & (NS - 1);
            const int hb = h * NB + bb;
            const float v = (acc[n][r] + bvv) * scale;
            const size_t idx = vtrans ? ((size_t)(hb * DKV + d) * NS + s)
                                      : ((size_t)(hb * NS + s) * DKV + d);
            out[idx] = f2bf(v);
        }
    }
}

// ---------------------------------------------------------------------------
// Fused attention (R6 structure), double-buffered K/V staging, 2-barrier
// schedule with counted vmcnt (never waits on stores). Pass 1: l=sum(exp2(s)).
// Pass 2: attn fp32 stored DIRECTLY from C-fragments (scalar stores, L2
// write-combined; no LDS read-back); P -> swizzled per-wave LDS for PV only.
// No setprio (T5 is null/negative on lockstep 2-phase schedules, m190).
// ---------------------------------------------------------------------------
__global__ __launch_bounds__(256, 4) void k_attn(const unsigned short* __restrict__ Qh,
                                                 const unsigned short* __restrict__ Kh,
                                                 const unsigned short* __restrict__ Vt,
                                                 float* __restrict__ attn,
                                                 unsigned short* __restrict__ Obuf)
{
    __shared__ __align__(16) char kld[2][8192];    // 64 keys x 64 dims bf16 (swizzled)
    __shared__ __align__(16) char vld[2][8192];    // 64 dims x 64 keys bf16 (swizzled)
    __shared__ __align__(16) char plds[4 * 2048];  // per-wave 16x64 bf16 P tile
    const int tid = threadIdx.x;
    const int l = tid & 63, w = tid >> 6;
    const int c = l & 15, g = l >> 4;
    constexpr int NT = NS / 64;                    // 32 key tiles

    // XCD-chunked swizzle: 1024 blocks, 8 XCDs -> 128 consecutive work-ids
    // (4 full hb slices) per XCD.
    const int bid = blockIdx.x;
    const int wid = (bid & 7) * 128 + (bid >> 3);
    const int hb = wid >> 5;
    const int q0 = (wid & 31) * 64 + w * 16;       // this wave's 16 q-rows
    char* myp = plds + w * 2048;

    const char* kbytes = (const char*)(Kh + (size_t)hb * NS * DKV);
    const char* vbytes = (const char*)(Vt + (size_t)hb * DKV * NS);

    const unsigned short* qb = Qh + ((size_t)hb * NS + q0 + c) * DKV + g * 8;
    const short8 qf0 = ld8(qb), qf1 = ld8(qb + 32);

    // staging source offsets (pre-swizzled): issue j covers LDS chunk
    // (w*2+j)*1024 + lane*16; row = chunk_row + (lane>>3), colb = (lane&7)*16.
    int koff[2], voff[2];
#pragma unroll
    for (int j = 0; j < 2; ++j) {
        const int D = (w * 2 + j) * 1024 + l * 16;
        const int row = D >> 7;
        const int scolb = (D & 127) ^ ((row & 7) << 4);
        koff[j] = row * 128 + scolb;               // K rows: 128 B stride in tile
        voff[j] = row * (NS * 2) + scolb;          // V^T rows: 4096 B global stride
    }
    const int swc = (c & 7) << 4;                  // read-side swizzle

    const int ldsbase = w * 2048;                  // this wave's chunk base

    // ---- pass 1: row sums of exp2(s), K double-buffered
    float ls[4] = {0.f, 0.f, 0.f, 0.f};
    {
        gl_lds16(kbytes + koff[0], kld[0] + ldsbase);
        gl_lds16(kbytes + koff[1], kld[0] + ldsbase + 1024);
        asm volatile("s_waitcnt vmcnt(0)" ::: "memory");
        bar();                                     // publish tile 0
        __builtin_amdgcn_sched_barrier(0);
        int cur = 0;
        for (int kt = 0; kt < NT; ++kt) {
            if (kt + 1 < NT) {
                const size_t nb = (size_t)(kt + 1) * 64 * 128;
                gl_lds16(kbytes + nb + koff[0], kld[cur ^ 1] + ldsbase);
                gl_lds16(kbytes + nb + koff[1], kld[cur ^ 1] + ldsbase + 1024);
            }
            if (kt > 0) {
                if (kt + 1 < NT) { asm volatile("s_waitcnt vmcnt(2)" ::: "memory"); }
                else             { asm volatile("s_waitcnt vmcnt(0)" ::: "memory"); }
                bar();                             // publish tile kt
                __builtin_amdgcn_sched_barrier(0);
            }
#pragma unroll
            for (int t = 0; t < 4; ++t) {
                const int rb = (t * 16 + c) * 128;
                const short8 b0 = *(const short8*)(kld[cur] + rb + ((g * 16) ^ swc));
                const short8 b1 = *(const short8*)(kld[cur] + rb + ((64 + g * 16) ^ swc));
                f32x4 z = {};
                z = mfma16(qf0, b0, z);
                z = mfma16(qf1, b1, z);
#pragma unroll
                for (int r = 0; r < 4; ++r) ls[r] += exp2f(z[r]);
            }
            bar();                                 // release kld[cur] for overwrite
            cur ^= 1;
        }
    }
    float li[4];
#pragma unroll
    for (int r = 0; r < 4; ++r) {
        float s = ls[r];
        s += __shfl_xor(s, 1);
        s += __shfl_xor(s, 2);
        s += __shfl_xor(s, 4);
        s += __shfl_xor(s, 8);
        li[r] = 1.0f / s;
    }

    // ---- pass 2
    f32x4 oacc[4] = {};
    // direct attn store base: lane covers rows q0+g*4+r (r=0..3), col c + t*16
    float* abase = attn + (size_t)hb * NS * NS + (size_t)(q0 + g * 4) * NS + c;

    {
        gl_lds16(kbytes + koff[0], kld[0] + ldsbase);
        gl_lds16(kbytes + koff[1], kld[0] + ldsbase + 1024);
        gl_lds16(vbytes + voff[0], vld[0] + ldsbase);
        gl_lds16(vbytes + voff[1], vld[0] + ldsbase + 1024);
        asm volatile("s_waitcnt vmcnt(0)" ::: "memory");
        bar();                                     // publish tile 0
        __builtin_amdgcn_sched_barrier(0);
        int cur = 0;
        for (int kt = 0; kt < NT; ++kt) {
            const int k0 = kt * 64;
            if (kt + 1 < NT) {
                const size_t nkb = (size_t)(k0 + 64) * 128;
                const size_t nvb = (size_t)(k0 + 64) * 2;
                gl_lds16(kbytes + nkb + koff[0], kld[cur ^ 1] + ldsbase);
                gl_lds16(kbytes + nkb + koff[1], kld[cur ^ 1] + ldsbase + 1024);
                gl_lds16(vbytes + nvb + voff[0], vld[cur ^ 1] + ldsbase);
                gl_lds16(vbytes + nvb + voff[1], vld[cur ^ 1] + ldsbase + 1024);
            }
            if (kt > 0) {
                // queue (old->new): L_kt(4), S_{kt-1}(16), L_{kt+1}(4) = 24.
                // vmcnt(20) drains L_kt only; never waits on stores.
                if (kt + 1 < NT) { asm volatile("s_waitcnt vmcnt(20)" ::: "memory"); }
                else             { asm volatile("s_waitcnt vmcnt(16)" ::: "memory"); }
                bar();                             // publish tile kt
                __builtin_amdgcn_sched_barrier(0);
            }
            // QK^T from K-LDS
            f32x4 sc[4];
#pragma unroll
            for (int t = 0; t < 4; ++t) {
                const int rb = (t * 16 + c) * 128;
                const short8 b0 = *(const short8*)(kld[cur] + rb + ((g * 16) ^ swc));
                const short8 b1 = *(const short8*)(kld[cur] + rb + ((64 + g * 16) ^ swc));
                f32x4 z = {};
                z = mfma16(qf0, b0, z);
                z = mfma16(qf1, b1, z);
                sc[t] = z;
            }
            // normalized P: direct fp32 scalar stores (from fragments) +
            // bf16 -> swizzled per-wave LDS for PV
#pragma unroll
            for (int t = 0; t < 4; ++t)
#pragma unroll
                for (int r = 0; r < 4; ++r) {
                    const float p = exp2f(sc[t][r]) * li[r];
                    abase[(size_t)r * NS + k0 + t * 16] = p;
                    const int row = g * 4 + r;
                    int by = row * 128 + (t * 16 + c) * 2;
                    by ^= (row & 7) << 4;
                    *(unsigned short*)(myp + by) = f2bf(p);
                }
            asm volatile("s_waitcnt lgkmcnt(0)" ::: "memory");
            __builtin_amdgcn_sched_barrier(0);
            // PV: A-frags of P from wave LDS, B-frags of V^T from block LDS
#pragma unroll
            for (int kk = 0; kk < 2; ++kk) {
                const short8 pa = *(const short8*)(myp + c * 128 + ((kk * 64 + g * 16) ^ swc));
#pragma unroll
                for (int n = 0; n < 4; ++n) {
                    const int rb = (n * 16 + c) * 128;
                    const short8 vb = *(const short8*)(vld[cur] + rb + ((kk * 64 + g * 16) ^ swc));
                    oacc[n] = mfma16(pa, vb, oacc[n]);
                }
            }
            bar();                                 // release buf[cur] for overwrite
            cur ^= 1;
        }
    }

    const int h = hb >> 2, bb = hb & 3;
#pragma unroll
    for (int n = 0; n < 4; ++n)
#pragma unroll
        for (int r = 0; r < 4; ++r) {
            const int q = q0 + g * 4 + r;
            const int dv = n * 16 + c;
            Obuf[((size_t)(bb * NS + q)) * DM + h * DKV + dv] = f2bf(oacc[n][r]);
        }
}

// ---------------------------------------------------------------------------
// FC: Y[m][d] = sum_f O[m][f]*Wfc[d][f] + bfc[d] + resid[m][d], bf16 out.
// ---------------------------------------------------------------------------
__global__ __launch_bounds__(256, 4) void k_fc(const unsigned short* __restrict__ O,
                                            const unsigned short* __restrict__ Wfc,
                                            const float* __restrict__ bfc,
                                            const float* __restrict__ resid,
                                            unsigned short* __restrict__ Y)
{
    const int tid = threadIdx.x;
    const int l = tid & 63, w = tid >> 6;
    const int c = l & 15, g = l >> 4;
    const int m0 = blockIdx.y * 64 + w * 16;
    const int f0 = blockIdx.x * 64;
    const int arow = m0 + c;

    f32x4 acc[4] = {};
    const unsigned short* aB = O + (size_t)arow * DM;
    for (int kb = 0; kb < DM; kb += 32) {
        short8 af = ld8(aB + kb + g * 8);
#pragma unroll
        for (int n = 0; n < 4; ++n) {
            short8 bf = ld8(Wfc + (size_t)(f0 + n * 16 + c) * DM + kb + g * 8);
            acc[n] = mfma16(af, bf, acc[n]);
        }
    }
#pragma unroll
    for (int n = 0; n < 4; ++n) {
        const int d = f0 + n * 16 + c;
        const float bv = bfc[d];
#pragma unroll
        for (int r = 0; r < 4; ++r) {
            const int m = m0 + g * 4 + r;
            const float v = acc[n][r] + bv + resid[(size_t)m * DM + d];
            Y[(size_t)m * DM + d] = f2bf(v);
        }
    }
}

// ---------------------------------------------------------------------------
// LayerNorm: one wave per row of 512.
// ---------------------------------------------------------------------------
__global__ __launch_bounds__(256) void k_ln(const unsigned short* __restrict__ Y,
                                            const float* __restrict__ gam,
                                            const float* __restrict__ bet,
                                            float* __restrict__ out)
{
    const int tid = threadIdx.x;
    const int l = tid & 63, w = tid >> 6;
    const int row = blockIdx.x * 4 + w;

    const short8 yv = ld8(Y + (size_t)row * DM + l * 8);
    float x[8];
#pragma unroll
    for (int j = 0; j < 8; ++j) x[j] = bf2f((unsigned short)yv[j]);

    float s = 0.f;
#pragma unroll
    for (int j = 0; j < 8; ++j) s += x[j];
#pragma unroll
    for (int mask = 1; mask <= 32; mask <<= 1) s += __shfl_xor(s, mask);
    const float mean = s * (1.0f / DM);

    float d2 = 0.f;
#pragma unroll
    for (int j = 0; j < 8; ++j) { const float t = x[j] - mean; d2 += t * t; }
#pragma unroll
    for (int mask = 1; mask <= 32; mask <<= 1) d2 += __shfl_xor(d2, mask);
    const float rstd = rsqrtf(d2 * (1.0f / DM) + 1e-5f);

#pragma unroll
    for (int j = 0; j < 8; ++j) {
        const int d = l * 8 + j;
        out[(size_t)row * DM + d] = (x[j] - mean) * rstd * gam[d] + bet[d];
    }
}

// ---------------------------------------------------------------------------
extern "C" void kernel_launch(void* const* d_in, const int* in_sizes, int n_in,
                              void* d_out, int out_size, void* d_ws, size_t ws_size,
                              hipStream_t stream)
{
    const float* q    = (const float*)d_in[0];
    const float* k    = (const float*)d_in[1];
    const float* v    = (const float*)d_in[2];
    const float* w_qs = (const float*)d_in[3];
    const float* b_qs = (const float*)d_in[4];
    const float* w_ks = (const float*)d_in[5];
    const float* b_ks = (const float*)d_in[6];
    const float* w_vs = (const float*)d_in[7];
    const float* b_vs = (const float*)d_in[8];
    const float* w_fc = (const float*)d_in[9];
    const float* b_fc = (const float*)d_in[10];
    const float* ln_g = (const float*)d_in[11];
    const float* ln_b = (const float*)d_in[12];

    char* ws = (char*)d_ws;
    unsigned short* Qh = (unsigned short*)(ws);                    //  8 MB bf16 [hb][s][64], scaled log2e/8
    unsigned short* Kh = (unsigned short*)(ws + (8u  << 20));      //  8 MB bf16 [hb][s][64]
    unsigned short* Vt = (unsigned short*)(ws + (16u << 20));      //  8 MB bf16 [hb][64][s]
    unsigned short* Ob = (unsigned short*)(ws + (24u << 20));      //  8 MB bf16 [m][512]
    unsigned short* Yb = (unsigned short*)(ws + (32u << 20));      //  8 MB bf16 [m][512]
    unsigned short* Wq = (unsigned short*)(ws + (40u << 20));      // 512 KB bf16 each
    unsigned short* Wk = Wq + (size_t)DM * DM;
    unsigned short* Wv = Wk + (size_t)DM * DM;
    unsigned short* Wf = Wv + (size_t)DM * DM;

    float* xout = (float*)d_out;
    float* attn = xout + (size_t)NB * NS * DM;  // output 1 region

    k_cvtw<<<dim3(128, 4), 256, 0, stream>>>(w_qs, w_ks, w_vs, w_fc, Wq, Wk, Wv, Wf);

    k_proj3<<<dim3(8, 128, 3), 256, 0, stream>>>(q, k, v, Wq, Wk, Wv,
                                                 b_qs, b_ks, b_vs, Qh, Kh, Vt);

    k_attn<<<1024, 256, 0, stream>>>(Qh, Kh, Vt, attn, Ob);

    k_fc<<<dim3(8, 128), 256, 0, stream>>>(Ob, Wf, b_fc, q, Yb);
    k_ln<<<NB * NS / 4, 256, 0, stream>>>(Yb, ln_g, ln_b, xout);
}

// Round 11
// 384.895 us; speedup vs baseline: 2.1328x; 1.0387x over previous
//
#include <hip/hip_runtime.h>
#include <hip/hip_bf16.h>

// Problem constants
constexpr int NB  = 4;     // batch
constexpr int NS  = 2048;  // sequence
constexpr int NH  = 8;     // heads
constexpr int DM  = 512;   // d_model
constexpr int DKV = 64;    // d_k = d_v
constexpr int HB  = NH * NB; // 32 (h,b) slices

typedef __attribute__((ext_vector_type(8))) short short8;
typedef __attribute__((ext_vector_type(4))) float f32x4;

__device__ inline unsigned short f2bf(float f) {
    unsigned u = __builtin_bit_cast(unsigned, f);
    u = (u + 0x7fffu + ((u >> 16) & 1u)) >> 16;   // RNE, finite inputs
    return (unsigned short)u;
}
__device__ inline float bf2f(unsigned short h) {
    unsigned u = ((unsigned)h) << 16;
    return __builtin_bit_cast(float, u);
}
__device__ inline short8 ld8(const unsigned short* p) { return *(const short8*)p; }

// Load 8 consecutive fp32, convert to bf16x8 fragment
__device__ inline short8 pack8(const float* p) {
    f32x4 a = *(const f32x4*)p;
    f32x4 b = *(const f32x4*)(p + 4);
    short8 r;
    r[0] = (short)f2bf(a[0]); r[1] = (short)f2bf(a[1]);
    r[2] = (short)f2bf(a[2]); r[3] = (short)f2bf(a[3]);
    r[4] = (short)f2bf(b[0]); r[5] = (short)f2bf(b[1]);
    r[6] = (short)f2bf(b[2]); r[7] = (short)f2bf(b[3]);
    return r;
}

__device__ inline f32x4 mfma16(short8 a, short8 b, f32x4 c) {
    return __builtin_amdgcn_mfma_f32_16x16x32_bf16(a, b, c, 0, 0, 0);
}

// async global->LDS, 16 bytes per lane; lds base must be wave-uniform
__device__ inline void gl_lds16(const void* g, void* l) {
    __builtin_amdgcn_global_load_lds(
        (const __attribute__((address_space(1))) unsigned*)g,
        (__attribute__((address_space(3))) unsigned*)l, 16, 0, 0);
}

__device__ inline void bar() { __builtin_amdgcn_s_barrier(); }

// ---------------------------------------------------------------------------
// Convert the four 512x512 fp32 weight matrices to bf16. grid (128, 4).
// ---------------------------------------------------------------------------
__global__ __launch_bounds__(256) void k_cvtw(const float* __restrict__ s0,
                                              const float* __restrict__ s1,
                                              const float* __restrict__ s2,
                                              const float* __restrict__ s3,
                                              unsigned short* __restrict__ d0,
                                              unsigned short* __restrict__ d1,
                                              unsigned short* __restrict__ d2,
                                              unsigned short* __restrict__ d3)
{
    const float* s; unsigned short* d;
    switch (blockIdx.y) {
        case 0:  s = s0; d = d0; break;
        case 1:  s = s1; d = d1; break;
        case 2:  s = s2; d = d2; break;
        default: s = s3; d = d3; break;
    }
    const size_t i = ((size_t)blockIdx.x * 256 + threadIdx.x) * 8;
    *(short8*)(d + i) = pack8(s + i);
}

// ---------------------------------------------------------------------------
// Projections (all three in one launch, z selects q/k/v). X is fp32 (packed
// to bf16 in-loop), W pre-converted bf16.
// z<2: out[hb][s][dkv] (Q scaled by log2e/8, K); z==2: out[hb][dkv][s] (V^T).
// ---------------------------------------------------------------------------
__global__ __launch_bounds__(256, 4) void k_proj3(const float* __restrict__ Xq,
                                                  const float* __restrict__ Xk,
                                                  const float* __restrict__ Xv,
                                                  const unsigned short* __restrict__ Wq,
                                                  const unsigned short* __restrict__ Wk,
                                                  const unsigned short* __restrict__ Wv,
                                                  const float* __restrict__ bq,
                                                  const float* __restrict__ bk,
                                                  const float* __restrict__ bv,
                                                  unsigned short* __restrict__ oq,
                                                  unsigned short* __restrict__ ok,
                                                  unsigned short* __restrict__ ov)
{
    const float* X; const unsigned short* W; const float* bias; unsigned short* out;
    float scale = 1.0f; int vtrans = 0;
    switch (blockIdx.z) {
        case 0:  X = Xq; W = Wq; bias = bq; out = oq;
                 scale = 0.125f * 1.44269504088896340736f; break;
        case 1:  X = Xk; W = Wk; bias = bk; out = ok; break;
        default: X = Xv; W = Wv; bias = bv; out = ov; vtrans = 1; break;
    }
    const int tid = threadIdx.x;
    const int l = tid & 63, w = tid >> 6;
    const int c = l & 15, g = l >> 4;
    const int m0 = blockIdx.y * 64 + w * 16;
    const int f0 = blockIdx.x * 64;
    const int arow = m0 + c;

    f32x4 acc[4] = {};
    const float* aB = X + (size_t)arow * DM;
    for (int kb = 0; kb < DM; kb += 32) {
        short8 af = pack8(aB + kb + g * 8);
#pragma unroll
        for (int n = 0; n < 4; ++n) {
            short8 bf = ld8(W + (size_t)(f0 + n * 16 + c) * DM + kb + g * 8);
            acc[n] = mfma16(af, bf, acc[n]);
        }
    }
#pragma unroll
    for (int n = 0; n < 4; ++n) {
        const int f = f0 + n * 16 + c;
        const int h = f >> 6, d = f & 63;
        const float bvv = bias[f];
#pragma unroll
        for (int r = 0; r < 4; ++r) {
            const int m = m0 + g * 4 + r;
            const int bb = m >> 11, s = m & (NS - 1);
            const int hb = h * NB + bb;
            const float v = (acc[n][r] + bvv) * scale;
            const size_t idx = vtrans ? ((size_t)(hb * DKV + d) * NS + s)
                                      : ((size_t)(hb * NS + s) * DKV + d);
            out[idx] = f2bf(v);
        }
    }
}

// ---------------------------------------------------------------------------
// Fused attention. Flat 40KB LDS, phase-overlaid:
//   pass 1: four 8KB K buffers (4-deep circular, prefetch distance 2,
//           ONE barrier per kt — stage target (kt+2)%4 is provably disjoint
//           from the slowest co-resident reader's buffer (kt-1)%4).
//   pass 2: R10 structure (2-deep K+V, 2-barrier, counted vmcnt; attn fp32
//           stored directly from C-fragments; P -> swizzled per-wave LDS
//           for PV only). XCD-chunked block swizzle. No setprio (T5 null
//           on lockstep schedules, m190).
// ---------------------------------------------------------------------------
__global__ __launch_bounds__(256, 4) void k_attn(const unsigned short* __restrict__ Qh,
                                                 const unsigned short* __restrict__ Kh,
                                                 const unsigned short* __restrict__ Vt,
                                                 float* __restrict__ attn,
                                                 unsigned short* __restrict__ Obuf)
{
    __shared__ __align__(16) char lds[40960];
    const int tid = threadIdx.x;
    const int l = tid & 63, w = tid >> 6;
    const int c = l & 15, g = l >> 4;
    constexpr int NT = NS / 64;                    // 32 key tiles

    // XCD-chunked swizzle: 1024 blocks, 8 XCDs -> 128 consecutive work-ids
    // (4 full hb slices) per XCD.
    const int bid = blockIdx.x;
    const int wid = (bid & 7) * 128 + (bid >> 3);
    const int hb = wid >> 5;
    const int q0 = (wid & 31) * 64 + w * 16;       // this wave's 16 q-rows
    char* myp = lds + 32768 + w * 2048;            // per-wave 16x64 bf16 P tile

    const char* kbytes = (const char*)(Kh + (size_t)hb * NS * DKV);
    const char* vbytes = (const char*)(Vt + (size_t)hb * DKV * NS);

    const unsigned short* qb = Qh + ((size_t)hb * NS + q0 + c) * DKV + g * 8;
    const short8 qf0 = ld8(qb), qf1 = ld8(qb + 32);

    // staging source offsets (pre-swizzled): issue j covers LDS chunk
    // (w*2+j)*1024 + lane*16; row = chunk_row + (lane>>3), colb = (lane&7)*16.
    int koff[2], voff[2];
#pragma unroll
    for (int j = 0; j < 2; ++j) {
        const int D = (w * 2 + j) * 1024 + l * 16;
        const int row = D >> 7;
        const int scolb = (D & 127) ^ ((row & 7) << 4);
        koff[j] = row * 128 + scolb;               // K rows: 128 B stride in tile
        voff[j] = row * (NS * 2) + scolb;          // V^T rows: 4096 B global stride
    }
    const int swc = (c & 7) << 4;                  // read-side swizzle

    const int ldsbase = w * 2048;                  // this wave's chunk base

    // ---- pass 1: row sums of exp2(s); K 4-deep circular, 1 barrier/kt
    float ls[4] = {0.f, 0.f, 0.f, 0.f};
    {
        // prologue: stage tiles 0,1 into bufs 0,1
        gl_lds16(kbytes + koff[0], lds + ldsbase);
        gl_lds16(kbytes + koff[1], lds + ldsbase + 1024);
        gl_lds16(kbytes + 8192 + koff[0], lds + 8192 + ldsbase);
        gl_lds16(kbytes + 8192 + koff[1], lds + 8192 + ldsbase + 1024);
        for (int kt = 0; kt < NT; ++kt) {
            if (kt + 2 < NT) {
                const int nxt = (kt + 2) & 3;
                const size_t nb = (size_t)(kt + 2) * 8192;
                gl_lds16(kbytes + nb + koff[0], lds + nxt * 8192 + ldsbase);
                gl_lds16(kbytes + nb + koff[1], lds + nxt * 8192 + ldsbase + 1024);
                // in flight: L_kt, L_{kt+1}, L_{kt+2} -> drain L_kt only
                asm volatile("s_waitcnt vmcnt(4)" ::: "memory");
            } else if (kt + 1 < NT) {
                asm volatile("s_waitcnt vmcnt(2)" ::: "memory");
            } else {
                asm volatile("s_waitcnt vmcnt(0)" ::: "memory");
            }
            bar();                                 // publish tile kt (single barrier)
            __builtin_amdgcn_sched_barrier(0);
            const char* kb = lds + (kt & 3) * 8192;
#pragma unroll
            for (int t = 0; t < 4; ++t) {
                const int rb = (t * 16 + c) * 128;
                const short8 b0 = *(const short8*)(kb + rb + ((g * 16) ^ swc));
                const short8 b1 = *(const short8*)(kb + rb + ((64 + g * 16) ^ swc));
                f32x4 z = {};
                z = mfma16(qf0, b0, z);
                z = mfma16(qf1, b1, z);
#pragma unroll
                for (int r = 0; r < 4; ++r) ls[r] += exp2f(z[r]);
            }
        }
    }
    float li[4];
#pragma unroll
    for (int r = 0; r < 4; ++r) {
        float s = ls[r];
        s += __shfl_xor(s, 1);
        s += __shfl_xor(s, 2);
        s += __shfl_xor(s, 4);
        s += __shfl_xor(s, 8);
        li[r] = 1.0f / s;
    }
    bar();   // protect pass-1 buffers from pass-2's overlaid staging

    // ---- pass 2 (R10 structure)
    char* kld0 = lds;          char* kld1 = lds + 8192;
    char* vld0 = lds + 16384;  char* vld1 = lds + 24576;
    f32x4 oacc[4] = {};
    // direct attn store base: lane covers rows q0+g*4+r (r=0..3), col c + t*16
    float* abase = attn + (size_t)hb * NS * NS + (size_t)(q0 + g * 4) * NS + c;

    {
        gl_lds16(kbytes + koff[0], kld0 + ldsbase);
        gl_lds16(kbytes + koff[1], kld0 + ldsbase + 1024);
        gl_lds16(vbytes + voff[0], vld0 + ldsbase);
        gl_lds16(vbytes + voff[1], vld0 + ldsbase + 1024);
        asm volatile("s_waitcnt vmcnt(0)" ::: "memory");
        bar();                                     // publish tile 0
        __builtin_amdgcn_sched_barrier(0);
        int cur = 0;
        for (int kt = 0; kt < NT; ++kt) {
            const int k0 = kt * 64;
            char* kldn = cur ? kld0 : kld1;
            char* vldn = cur ? vld0 : vld1;
            char* kldc = cur ? kld1 : kld0;
            char* vldc = cur ? vld1 : vld0;
            if (kt + 1 < NT) {
                const size_t nkb = (size_t)(k0 + 64) * 128;
                const size_t nvb = (size_t)(k0 + 64) * 2;
                gl_lds16(kbytes + nkb + koff[0], kldn + ldsbase);
                gl_lds16(kbytes + nkb + koff[1], kldn + ldsbase + 1024);
                gl_lds16(vbytes + nvb + voff[0], vldn + ldsbase);
                gl_lds16(vbytes + nvb + voff[1], vldn + ldsbase + 1024);
            }
            if (kt > 0) {
                // queue (old->new): L_kt(4), S_{kt-1}(16), L_{kt+1}(4) = 24.
                // vmcnt(20) drains L_kt only; never waits on stores.
                if (kt + 1 < NT) { asm volatile("s_waitcnt vmcnt(20)" ::: "memory"); }
                else             { asm volatile("s_waitcnt vmcnt(16)" ::: "memory"); }
                bar();                             // publish tile kt
                __builtin_amdgcn_sched_barrier(0);
            }
            // QK^T from K-LDS
            f32x4 sc[4];
#pragma unroll
            for (int t = 0; t < 4; ++t) {
                const int rb = (t * 16 + c) * 128;
                const short8 b0 = *(const short8*)(kldc + rb + ((g * 16) ^ swc));
                const short8 b1 = *(const short8*)(kldc + rb + ((64 + g * 16) ^ swc));
                f32x4 z = {};
                z = mfma16(qf0, b0, z);
                z = mfma16(qf1, b1, z);
                sc[t] = z;
            }
            // normalized P: direct fp32 scalar stores (from fragments) +
            // bf16 -> swizzled per-wave LDS for PV
#pragma unroll
            for (int t = 0; t < 4; ++t)
#pragma unroll
                for (int r = 0; r < 4; ++r) {
                    const float p = exp2f(sc[t][r]) * li[r];
                    abase[(size_t)r * NS + k0 + t * 16] = p;
                    const int row = g * 4 + r;
                    int by = row * 128 + (t * 16 + c) * 2;
                    by ^= (row & 7) << 4;
                    *(unsigned short*)(myp + by) = f2bf(p);
                }
            asm volatile("s_waitcnt lgkmcnt(0)" ::: "memory");
            __builtin_amdgcn_sched_barrier(0);
            // PV: A-frags of P from wave LDS, B-frags of V^T from block LDS
#pragma unroll
            for (int kk = 0; kk < 2; ++kk) {
                const short8 pa = *(const short8*)(myp + c * 128 + ((kk * 64 + g * 16) ^ swc));
#pragma unroll
                for (int n = 0; n < 4; ++n) {
                    const int rb = (n * 16 + c) * 128;
                    const short8 vb = *(const short8*)(vldc + rb + ((kk * 64 + g * 16) ^ swc));
                    oacc[n] = mfma16(pa, vb, oacc[n]);
                }
            }
            bar();                                 // release buf[cur] for overwrite
            cur ^= 1;
        }
    }

    const int h = hb >> 2, bb = hb & 3;
#pragma unroll
    for (int n = 0; n < 4; ++n)
#pragma unroll
        for (int r = 0; r < 4; ++r) {
            const int q = q0 + g * 4 + r;
            const int dv = n * 16 + c;
            Obuf[((size_t)(bb * NS + q)) * DM + h * DKV + dv] = f2bf(oacc[n][r]);
        }
}

// ---------------------------------------------------------------------------
// FC: Y[m][d] = sum_f O[m][f]*Wfc[d][f] + bfc[d] + resid[m][d], bf16 out.
// ---------------------------------------------------------------------------
__global__ __launch_bounds__(256, 4) void k_fc(const unsigned short* __restrict__ O,
                                            const unsigned short* __restrict__ Wfc,
                                            const float* __restrict__ bfc,
                                            const float* __restrict__ resid,
                                            unsigned short* __restrict__ Y)
{
    const int tid = threadIdx.x;
    const int l = tid & 63, w = tid >> 6;
    const int c = l & 15, g = l >> 4;
    const int m0 = blockIdx.y * 64 + w * 16;
    const int f0 = blockIdx.x * 64;
    const int arow = m0 + c;

    f32x4 acc[4] = {};
    const unsigned short* aB = O + (size_t)arow * DM;
    for (int kb = 0; kb < DM; kb += 32) {
        short8 af = ld8(aB + kb + g * 8);
#pragma unroll
        for (int n = 0; n < 4; ++n) {
            short8 bf = ld8(Wfc + (size_t)(f0 + n * 16 + c) * DM + kb + g * 8);
            acc[n] = mfma16(af, bf, acc[n]);
        }
    }
#pragma unroll
    for (int n = 0; n < 4; ++n) {
        const int d = f0 + n * 16 + c;
        const float bv = bfc[d];
#pragma unroll
        for (int r = 0; r < 4; ++r) {
            const int m = m0 + g * 4 + r;
            const float v = acc[n][r] + bv + resid[(size_t)m * DM + d];
            Y[(size_t)m * DM + d] = f2bf(v);
        }
    }
}

// ---------------------------------------------------------------------------
// LayerNorm: one wave per row of 512.
// ---------------------------------------------------------------------------
__global__ __launch_bounds__(256) void k_ln(const unsigned short* __restrict__ Y,
                                            const float* __restrict__ gam,
                                            const float* __restrict__ bet,
                                            float* __restrict__ out)
{
    const int tid = threadIdx.x;
    const int l = tid & 63, w = tid >> 6;
    const int row = blockIdx.x * 4 + w;

    const short8 yv = ld8(Y + (size_t)row * DM + l * 8);
    float x[8];
#pragma unroll
    for (int j = 0; j < 8; ++j) x[j] = bf2f((unsigned short)yv[j]);

    float s = 0.f;
#pragma unroll
    for (int j = 0; j < 8; ++j) s += x[j];
#pragma unroll
    for (int mask = 1; mask <= 32; mask <<= 1) s += __shfl_xor(s, mask);
    const float mean = s * (1.0f / DM);

    float d2 = 0.f;
#pragma unroll
    for (int j = 0; j < 8; ++j) { const float t = x[j] - mean; d2 += t * t; }
#pragma unroll
    for (int mask = 1; mask <= 32; mask <<= 1) d2 += __shfl_xor(d2, mask);
    const float rstd = rsqrtf(d2 * (1.0f / DM) + 1e-5f);

#pragma unroll
    for (int j = 0; j < 8; ++j) {
        const int d = l * 8 + j;
        out[(size_t)row * DM + d] = (x[j] - mean) * rstd * gam[d] + bet[d];
    }
}

// ---------------------------------------------------------------------------
extern "C" void kernel_launch(void* const* d_in, const int* in_sizes, int n_in,
                              void* d_out, int out_size, void* d_ws, size_t ws_size,
                              hipStream_t stream)
{
    const float* q    = (const float*)d_in[0];
    const float* k    = (const float*)d_in[1];
    const float* v    = (const float*)d_in[2];
    const float* w_qs = (const float*)d_in[3];
    const float* b_qs = (const float*)d_in[4];
    const float* w_ks = (const float*)d_in[5];
    const float* b_ks = (const float*)d_in[6];
    const float* w_vs = (const float*)d_in[7];
    const float* b_vs = (const float*)d_in[8];
    const float* w_fc = (const float*)d_in[9];
    const float* b_fc = (const float*)d_in[10];
    const float* ln_g = (const float*)d_in[11];
    const float* ln_b = (const float*)d_in[12];

    char* ws = (char*)d_ws;
    unsigned short* Qh = (unsigned short*)(ws);                    //  8 MB bf16 [hb][s][64], scaled log2e/8
    unsigned short* Kh = (unsigned short*)(ws + (8u  << 20));      //  8 MB bf16 [hb][s][64]
    unsigned short* Vt = (unsigned short*)(ws + (16u << 20));      //  8 MB bf16 [hb][64][s]
    unsigned short* Ob = (unsigned short*)(ws + (24u << 20));      //  8 MB bf16 [m][512]
    unsigned short* Yb = (unsigned short*)(ws + (32u << 20));      //  8 MB bf16 [m][512]
    unsigned short* Wq = (unsigned short*)(ws + (40u << 20));      // 512 KB bf16 each
    unsigned short* Wk = Wq + (size_t)DM * DM;
    unsigned short* Wv = Wk + (size_t)DM * DM;
    unsigned short* Wf = Wv + (size_t)DM * DM;

    float* xout = (float*)d_out;
    float* attn = xout + (size_t)NB * NS * DM;  // output 1 region

    k_cvtw<<<dim3(128, 4), 256, 0, stream>>>(w_qs, w_ks, w_vs, w_fc, Wq, Wk, Wv, Wf);

    k_proj3<<<dim3(8, 128, 3), 256, 0, stream>>>(q, k, v, Wq, Wk, Wv,
                                                 b_qs, b_ks, b_vs, Qh, Kh, Vt);

    k_attn<<<1024, 256, 0, stream>>>(Qh, Kh, Vt, attn, Ob);

    k_fc<<<dim3(8, 128), 256, 0, stream>>>(Ob, Wf, b_fc, q, Yb);
    k_ln<<<NB * NS / 4, 256, 0, stream>>>(Yb, ln_g, ln_b, xout);
}